// Round 8
// baseline (48.376 us; speedup 1.0000x reference)
//
#include <hip/hip_runtime.h>

// GetScalars: per (b,n) atom, REAL part of complex Gram matrices over the
// m-dim for l=0..3 plus interleaved l=0 passthrough.
//
// Ground truth (R5): out_size counts complex64 elements (32768*1056), buffer
// holds out_size float32, validation compares real parts only. Writing
// 2112 floats/atom faults (R0/R3/R4 crashes).
//
// v4 = v2 + nontemporal loads/stores via native clang vector type
// (HIP_vector_type<float,4> is a struct -> rejected by the builtin; R7).
// Addresses identical to the proven v2 kernel.

typedef float fx4 __attribute__((ext_vector_type(4)));

__global__ __launch_bounds__(256) void getscalars_real_v4(
    const float* __restrict__ p0re, const float* __restrict__ p0im,
    const float* __restrict__ p1re, const float* __restrict__ p1im,
    const float* __restrict__ p2re, const float* __restrict__ p2im,
    const float* __restrict__ p3re, const float* __restrict__ p3im,
    float* __restrict__ out)
{
    const int t = threadIdx.x;
    const size_t a = (size_t)blockIdx.x;

    // LDS float layout: [0,16) p0re | [16,32) p0im | [32,80) p1re |
    // [80,128) p1im | [128,208) p2re | [208,288) p2im | [288,400) p3re |
    // [400,512) p3im
    __shared__ float s[512];
    fx4* s4 = (fx4*)s;

    if (t < 128) {                      // 128 x 16B = 512 floats
        const fx4* src; int off;
        if (t < 8)       { src = (const fx4*)((t < 4   ? p0re : p0im) + a * 16);  off = t & 3; }
        else if (t < 32) { src = (const fx4*)((t < 20  ? p1re : p1im) + a * 48);  off = (t < 20)  ? t - 8  : t - 20; }
        else if (t < 72) { src = (const fx4*)((t < 52  ? p2re : p2im) + a * 80);  off = (t < 52)  ? t - 32 : t - 52; }
        else             { src = (const fx4*)((t < 100 ? p3re : p3im) + a * 112); off = (t < 100) ? t - 72 : t - 100; }
        s4[t] = __builtin_nontemporal_load(src + off);
    }
    __syncthreads();

    fx4* obase = (fx4*)(out + a * 1056);   // 264 quads per atom

    // part0 (32 floats = 8 quads): (re0[2j], im0[2j], re0[2j+1], im0[2j+1])
    if (t < 8) {
        fx4 v = { s[2 * t], s[16 + 2 * t], s[2 * t + 1], s[16 + 2 * t + 1] };
        __builtin_nontemporal_store(v, obase + t);
    }

    // Gram real part: wave w = l; lane e covers row c1 = e>>2,
    // cols [4*(e&3), 4*(e&3)+4).
    const int e  = t & 63;
    const int c1 = e >> 2;
    const int q2 = e & 3;
    const int w  = t >> 6;

    fx4 acc = { 0.0f, 0.0f, 0.0f, 0.0f };

#define GS_GRAM_Q(RO, IO, M)                                                  \
    {                                                                         \
        _Pragma("unroll")                                                     \
        for (int m = 0; m < (M); ++m) {                                       \
            const float r1 = s[(RO) + m * 16 + c1];                           \
            const float i1 = s[(IO) + m * 16 + c1];                           \
            const fx4   r2 = s4[((RO) >> 2) + m * 4 + q2];                    \
            const fx4   i2 = s4[((IO) >> 2) + m * 4 + q2];                    \
            acc += r1 * r2 + i1 * i2;                                         \
        }                                                                     \
    }

    if      (w == 0) GS_GRAM_Q(0,   16,  1)
    else if (w == 1) GS_GRAM_Q(32,  80,  3)
    else if (w == 2) GS_GRAM_Q(128, 208, 5)
    else             GS_GRAM_Q(288, 400, 7)
#undef GS_GRAM_Q

    __builtin_nontemporal_store(acc, obase + 8 + w * 64 + e);
}

// ---- Defensive fallback (R2-proven, only taken if out really holds pairs) --

#define GS_STAGE_LDS()                                                        \
    __shared__ float s[512];                                                  \
    {                                                                         \
        const size_t a = (size_t)blockIdx.x;                                  \
        for (int f = threadIdx.x; f < 512; f += 256) {                        \
            const float* src; int off;                                        \
            if (f < 16)       { src = p0re + a * 16;  off = f; }              \
            else if (f < 32)  { src = p0im + a * 16;  off = f - 16; }         \
            else if (f < 80)  { src = p1re + a * 48;  off = f - 32; }         \
            else if (f < 128) { src = p1im + a * 48;  off = f - 80; }         \
            else if (f < 208) { src = p2re + a * 80;  off = f - 128; }        \
            else if (f < 288) { src = p2im + a * 80;  off = f - 208; }        \
            else if (f < 400) { src = p3re + a * 112; off = f - 288; }        \
            else              { src = p3im + a * 112; off = f - 400; }        \
            s[f] = src[off];                                                  \
        }                                                                     \
    }                                                                         \
    __syncthreads();

__global__ __launch_bounds__(256) void getscalars_pairs(
    const float* __restrict__ p0re, const float* __restrict__ p0im,
    const float* __restrict__ p1re, const float* __restrict__ p1im,
    const float* __restrict__ p2re, const float* __restrict__ p2im,
    const float* __restrict__ p3re, const float* __restrict__ p3im,
    float* __restrict__ out)
{
    const int t = threadIdx.x;
    GS_STAGE_LDS();

    float2* cbase = (float2*)(out + (size_t)blockIdx.x * 2112);

    if (t < 32) {
        float vr = (t & 1) ? s[16 + (t >> 1)] : s[t >> 1];
        cbase[t] = make_float2(vr, 0.0f);
    }

    const int c1 = t >> 4, c2 = t & 15;
    const int roff[4] = { 0, 32, 128, 288 };
    const int ioff[4] = { 16, 80, 208, 400 };
    const int Ms[4]   = { 1, 3, 5, 7 };

    #pragma unroll
    for (int l = 0; l < 4; ++l) {
        const float* re = s + roff[l];
        const float* im = s + ioff[l];
        float gr = 0.0f, gi = 0.0f;
        #pragma unroll
        for (int m = 0; m < Ms[l]; ++m) {
            float r1 = re[m * 16 + c1], r2 = re[m * 16 + c2];
            float i1 = im[m * 16 + c1], i2 = im[m * 16 + c2];
            gr += r1 * r2 + i1 * i2;
            gi += i1 * r2 - r1 * i2;
        }
        cbase[32 + l * 256 + t] = make_float2(gr, gi);
    }
}

extern "C" void kernel_launch(void* const* d_in, const int* in_sizes, int n_in,
                              void* d_out, int out_size, void* d_ws, size_t ws_size,
                              hipStream_t stream) {
    const float* p0re = (const float*)d_in[0];
    const float* p0im = (const float*)d_in[1];
    const float* p1re = (const float*)d_in[2];
    const float* p1im = (const float*)d_in[3];
    const float* p2re = (const float*)d_in[4];
    const float* p2im = (const float*)d_in[5];
    const float* p3re = (const float*)d_in[6];
    const float* p3im = (const float*)d_in[7];
    float* out = (float*)d_out;

    const int atoms = in_sizes[0] / 16;          // B*N
    const long long fpa = (long long)out_size / atoms;

    if (fpa >= 2112) {
        getscalars_pairs<<<atoms, 256, 0, stream>>>(
            p0re, p0im, p1re, p1im, p2re, p2im, p3re, p3im, out);
    } else {
        getscalars_real_v4<<<atoms, 256, 0, stream>>>(
            p0re, p0im, p1re, p1im, p2re, p2im, p3re, p3im, out);
    }
}

// Round 9
// 37.871 us; speedup vs baseline: 1.2774x; 1.2774x over previous
//
#include <hip/hip_runtime.h>

// GetScalars: per (b,n) atom, REAL part of complex Gram matrices over the
// m-dim for l=0..3 plus interleaved l=0 passthrough.
//
// Ground truth (R5): out_size counts complex64 elements (32768*1056), buffer
// holds out_size float32, validation compares real parts only.
// R8: nontemporal hints HURT (38.2 -> 48.4 us) — L2/L3 were helping both
// streams. Reverted.
//
// v5: 4 atoms per block. All 256 threads issue 2 staging loads (v2 had only
// 128 threads issue 1), 4x compute/store work per thread post-barrier,
// 8192 blocks instead of 32768. Same bytes, same proven v2 address math
// per atom (tt = id & 127 mapping).

typedef float fx4 __attribute__((ext_vector_type(4)));

__global__ __launch_bounds__(256) void getscalars_real_v5(
    const float* __restrict__ p0re, const float* __restrict__ p0im,
    const float* __restrict__ p1re, const float* __restrict__ p1im,
    const float* __restrict__ p2re, const float* __restrict__ p2im,
    const float* __restrict__ p3re, const float* __restrict__ p3im,
    float* __restrict__ out)
{
    const int t = threadIdx.x;
    const size_t a0 = (size_t)blockIdx.x * 4;

    // Per-atom LDS float layout (atom-major, 512 floats each):
    // [0,16) p0re | [16,32) p0im | [32,80) p1re | [80,128) p1im |
    // [128,208) p2re | [208,288) p2im | [288,400) p3re | [400,512) p3im
    __shared__ float s[4 * 512];
    fx4* s4 = (fx4*)s;

    // Staging: 512 quads total, 256 threads x 2. id = al*128 + tt.
    #pragma unroll
    for (int k2 = 0; k2 < 2; ++k2) {
        const int id = t + k2 * 256;
        const int al = id >> 7;
        const int tt = id & 127;
        const size_t a = a0 + al;
        const fx4* src; int off;
        if (tt < 8)       { src = (const fx4*)((tt < 4   ? p0re : p0im) + a * 16);  off = tt & 3; }
        else if (tt < 32) { src = (const fx4*)((tt < 20  ? p1re : p1im) + a * 48);  off = (tt < 20)  ? tt - 8  : tt - 20; }
        else if (tt < 72) { src = (const fx4*)((tt < 52  ? p2re : p2im) + a * 80);  off = (tt < 52)  ? tt - 32 : tt - 52; }
        else              { src = (const fx4*)((tt < 100 ? p3re : p3im) + a * 112); off = (tt < 100) ? tt - 72 : tt - 100; }
        s4[id] = src[off];
    }
    __syncthreads();

    fx4* oq = (fx4*)out;   // 264 quads per atom

    // part0: 4 atoms x 8 quads = 32 stores; quad j of atom al:
    // (re0[2j], im0[2j], re0[2j+1], im0[2j+1])
    if (t < 32) {
        const int al = t >> 3;
        const int j  = t & 7;
        const float* sa = s + al * 512;
        fx4 v = { sa[2 * j], sa[16 + 2 * j], sa[2 * j + 1], sa[16 + 2 * j + 1] };
        oq[(a0 + al) * 264 + j] = v;
    }

    // Gram real part: wave w = l; lane e covers row c1 = e>>2,
    // cols [4*(e&3), 4*(e&3)+4). Repeated for each of the 4 atoms.
    const int e  = t & 63;
    const int c1 = e >> 2;
    const int q2 = e & 3;
    const int w  = t >> 6;

#define GS_GRAM_Q(K, RO, IO, M)                                               \
    {                                                                         \
        _Pragma("unroll")                                                     \
        for (int m = 0; m < (M); ++m) {                                       \
            const float r1 = s[(K) * 512 + (RO) + m * 16 + c1];               \
            const float i1 = s[(K) * 512 + (IO) + m * 16 + c1];               \
            const fx4   r2 = s4[(K) * 128 + ((RO) >> 2) + m * 4 + q2];        \
            const fx4   i2 = s4[(K) * 128 + ((IO) >> 2) + m * 4 + q2];        \
            acc += r1 * r2 + i1 * i2;                                         \
        }                                                                     \
    }

    #pragma unroll
    for (int k = 0; k < 4; ++k) {
        fx4 acc = { 0.0f, 0.0f, 0.0f, 0.0f };
        if      (w == 0) GS_GRAM_Q(k, 0,   16,  1)
        else if (w == 1) GS_GRAM_Q(k, 32,  80,  3)
        else if (w == 2) GS_GRAM_Q(k, 128, 208, 5)
        else             GS_GRAM_Q(k, 288, 400, 7)
        oq[(a0 + k) * 264 + 8 + w * 64 + e] = acc;
    }
#undef GS_GRAM_Q
}

// ---- Per-atom fallback (proven v2) for atoms not divisible by 4 -----------

__global__ __launch_bounds__(256) void getscalars_real_v2(
    const float* __restrict__ p0re, const float* __restrict__ p0im,
    const float* __restrict__ p1re, const float* __restrict__ p1im,
    const float* __restrict__ p2re, const float* __restrict__ p2im,
    const float* __restrict__ p3re, const float* __restrict__ p3im,
    float* __restrict__ out, int abase)
{
    const int t = threadIdx.x;
    const size_t a = (size_t)blockIdx.x + abase;

    __shared__ float s[512];
    fx4* s4 = (fx4*)s;

    if (t < 128) {
        const fx4* src; int off;
        if (t < 8)       { src = (const fx4*)((t < 4   ? p0re : p0im) + a * 16);  off = t & 3; }
        else if (t < 32) { src = (const fx4*)((t < 20  ? p1re : p1im) + a * 48);  off = (t < 20)  ? t - 8  : t - 20; }
        else if (t < 72) { src = (const fx4*)((t < 52  ? p2re : p2im) + a * 80);  off = (t < 52)  ? t - 32 : t - 52; }
        else             { src = (const fx4*)((t < 100 ? p3re : p3im) + a * 112); off = (t < 100) ? t - 72 : t - 100; }
        s4[t] = src[off];
    }
    __syncthreads();

    fx4* obase = (fx4*)(out + a * 1056);

    if (t < 8) {
        fx4 v = { s[2 * t], s[16 + 2 * t], s[2 * t + 1], s[16 + 2 * t + 1] };
        obase[t] = v;
    }

    const int e  = t & 63;
    const int c1 = e >> 2;
    const int q2 = e & 3;
    const int w  = t >> 6;

    fx4 acc = { 0.0f, 0.0f, 0.0f, 0.0f };

#define GS_GRAM_Q(RO, IO, M)                                                  \
    {                                                                         \
        _Pragma("unroll")                                                     \
        for (int m = 0; m < (M); ++m) {                                       \
            const float r1 = s[(RO) + m * 16 + c1];                           \
            const float i1 = s[(IO) + m * 16 + c1];                           \
            const fx4   r2 = s4[((RO) >> 2) + m * 4 + q2];                    \
            const fx4   i2 = s4[((IO) >> 2) + m * 4 + q2];                    \
            acc += r1 * r2 + i1 * i2;                                         \
        }                                                                     \
    }

    if      (w == 0) GS_GRAM_Q(0,   16,  1)
    else if (w == 1) GS_GRAM_Q(32,  80,  3)
    else if (w == 2) GS_GRAM_Q(128, 208, 5)
    else             GS_GRAM_Q(288, 400, 7)
#undef GS_GRAM_Q

    obase[8 + w * 64 + e] = acc;
}

extern "C" void kernel_launch(void* const* d_in, const int* in_sizes, int n_in,
                              void* d_out, int out_size, void* d_ws, size_t ws_size,
                              hipStream_t stream) {
    const float* p0re = (const float*)d_in[0];
    const float* p0im = (const float*)d_in[1];
    const float* p1re = (const float*)d_in[2];
    const float* p1im = (const float*)d_in[3];
    const float* p2re = (const float*)d_in[4];
    const float* p2im = (const float*)d_in[5];
    const float* p3re = (const float*)d_in[6];
    const float* p3im = (const float*)d_in[7];
    float* out = (float*)d_out;

    const int atoms  = in_sizes[0] / 16;   // B*N
    const int blocks = atoms >> 2;
    const int tail   = atoms & 3;

    if (blocks > 0) {
        getscalars_real_v5<<<blocks, 256, 0, stream>>>(
            p0re, p0im, p1re, p1im, p2re, p2im, p3re, p3im, out);
    }
    if (tail > 0) {
        getscalars_real_v2<<<tail, 256, 0, stream>>>(
            p0re, p0im, p1re, p1im, p2re, p2im, p3re, p3im, out, blocks * 4);
    }
}